// Round 6
// baseline (508.128 us; speedup 1.0000x reference)
//
#include <hip/hip_runtime.h>
#include <hip/hip_bf16.h>

// Attention fwd: B=4 H=16 S=2048 D=64, fp32 in/out, softmax(QK^T/8)V
// Round 6: V pre-permuted so cvt_pk outputs ARE the PV A-fragment (no P LDS),
// 16KB LDS -> 8 blocks/CU, acc init biased by -m_run (no subs on deferred
// tiles), per-lane l partials (epilogue reduce), coalesced prep_v.

constexpr int Sdim = 2048;
constexpr int Ddim = 64;
constexpr int QBLK = 64;
constexpr int KVBLK = 64;
constexpr int NW = 4;
constexpr int NBH = 64;             // B*H
constexpr int NT = Sdim / KVBLK;    // 32
constexpr float QSCALE = 0.125f * 1.44269504f; // 1/sqrt(64) * log2(e)
constexpr float DEFER_THR = 11.0f;  // log2 units: p <= 2^11

typedef __attribute__((ext_vector_type(8))) short short8;
typedef __attribute__((ext_vector_type(4))) float f32x4;
typedef __attribute__((ext_vector_type(4))) unsigned short ushort4v;

typedef __attribute__((address_space(1))) const unsigned int GU32;
typedef __attribute__((address_space(3))) unsigned int LU32;

__device__ __forceinline__ unsigned short f2bf(float f) {
    union { float f; unsigned int u; } v; v.f = f;
    unsigned int r = v.u + 0x7FFFu + ((v.u >> 16) & 1u);   // RNE
    return (unsigned short)(r >> 16);
}

__device__ __forceinline__ unsigned int cvt_pk_bf16(float lo, float hi) {
    unsigned int r;
    asm("v_cvt_pk_bf16_f32 %0, %1, %2" : "=v"(r) : "v"(lo), "v"(hi));
    return r;
}

__device__ __forceinline__ void gload_lds16(const unsigned short* g, unsigned short* l) {
    __builtin_amdgcn_global_load_lds((GU32*)g, (LU32*)l, 16, 0, 0);
}

// ---- pre-pass: K -> bf16, swizzled within each row: elem (s, c) at c ^ ((s&7)<<3)
__global__ __launch_bounds__(256)
void prep_k(const float* __restrict__ Kg, unsigned short* __restrict__ Kbf) {
    size_t idx = ((size_t)blockIdx.x * 256 + threadIdx.x) * 4;
    int c0 = (int)(idx & 63);
    size_t row = idx >> 6;
    int swz = ((int)row & 7) << 3;
    float4 f = *(const float4*)(Kg + idx);
    ushort4v h;
    h.x = f2bf(f.x); h.y = f2bf(f.y); h.z = f2bf(f.z); h.w = f2bf(f.w);
    *(ushort4v*)(Kbf + (row << 6) + (c0 ^ swz)) = h;
}

// ---- pre-pass: V -> bf16, transposed + kv-PERMUTED per 64-tile:
// Vtb[d][ s ^ ((d&7)<<3) ] = V[kv][d]  with  s = 32kc+8g+4h+r  for
// kv = 32kc+16h+4g+r.  Coalesced via LDS-staged transpose.
__global__ __launch_bounds__(256)
void prep_v(const float* __restrict__ Vg, unsigned short* __restrict__ Vtb) {
    __shared__ unsigned short Vl[KVBLK][Ddim + 4];   // +4 pad: stagger banks
    int bh = blockIdx.x >> 5, t = blockIdx.x & 31;
    const float* src = Vg + ((size_t)bh * Sdim + t * KVBLK) * Ddim;
    unsigned short* dst = Vtb + ((size_t)bh * NT + t) * (Ddim * KVBLK);

    {   // coalesced read: 4 lanes cover one 64-float row
        int kv = threadIdx.x >> 2;
        int dq = (threadIdx.x & 3) * 16;
#pragma unroll
        for (int i = 0; i < 4; ++i) {
            float4 f = *(const float4*)(src + (size_t)kv * Ddim + dq + 4 * i);
            ushort4v h;
            h.x = f2bf(f.x); h.y = f2bf(f.y); h.z = f2bf(f.z); h.w = f2bf(f.w);
            *(ushort4v*)&Vl[kv][dq + 4 * i] = h;
        }
    }
    __syncthreads();
    {   // transposed, permuted, swizzled write: 4 lanes cover one 64-elem d-row
        int d  = threadIdx.x >> 2;
        int sc = (threadIdx.x & 3) * 16;
        int swzd = (d & 7) << 3;
#pragma unroll
        for (int u = 0; u < 4; ++u) {
            int s0 = sc + 4 * u;                       // multiple of 4
            int kc = s0 >> 5, g = (s0 >> 3) & 3, h = (s0 >> 2) & 1;
            int kvb = 32 * kc + 16 * h + 4 * g;
            ushort4v o;
            o.x = Vl[kvb + 0][d]; o.y = Vl[kvb + 1][d];
            o.z = Vl[kvb + 2][d]; o.w = Vl[kvb + 3][d];
            *(ushort4v*)(dst + (size_t)d * KVBLK + (s0 ^ swzd)) = o;
        }
    }
}

// ================= fast main kernel =================
__global__ __launch_bounds__(256, 8)
void attn_fwd_fast(const float* __restrict__ Qg, const unsigned short* __restrict__ Kbf,
                   const unsigned short* __restrict__ Vtb, float* __restrict__ Og)
{
    __shared__ unsigned short Kt[KVBLK][Ddim];    // [kv][d], row-swizzled
    __shared__ unsigned short Vt[Ddim][KVBLK];    // [d][perm(kv)], row-swizzled

    const int tid = threadIdx.x;
    const int w   = tid >> 6;
    const int l   = tid & 63;
    const int g   = l >> 4;
    const int q   = l & 15;
    const int swz = (q & 7) << 3;

    const int bh = blockIdx.y;
    const size_t base = (size_t)bh * Sdim * Ddim;
    const int q0 = blockIdx.x * QBLK;

    // Q fragments (B-operand of swapped QK^T), scale*log2e folded in
    short8 qf[2];
    {
        const float* qrow = Qg + base + (size_t)(q0 + w * 16 + q) * Ddim;
#pragma unroll
        for (int kc = 0; kc < 2; ++kc) {
            float fv[8];
            *(float4*)(fv)     = *(const float4*)(qrow + kc * 32 + g * 8);
            *(float4*)(fv + 4) = *(const float4*)(qrow + kc * 32 + g * 8 + 4);
            short8 r;
#pragma unroll
            for (int j = 0; j < 8; ++j) r[j] = (short)f2bf(fv[j] * QSCALE);
            qf[kc] = r;
        }
    }

    f32x4 o[4];
#pragma unroll
    for (int dt = 0; dt < 4; ++dt)
#pragma unroll
        for (int r = 0; r < 4; ++r) o[dt][r] = 0.0f;
    float m_run = 0.0f;      // log2-domain; scores ~O(7), defer bound keeps p<=2^11
    float l_part = 0.0f;     // per-lane partial (16 of 64 kv per tile); reduced at end

    union PU { unsigned int u[4]; short8 s8; };

    for (int t = 0; t < NT; ++t) {
        __syncthreads();
        {
            const unsigned short* ksrc = Kbf + base + (size_t)t * (KVBLK * Ddim);
            const unsigned short* vsrc = Vtb + base + (size_t)t * (KVBLK * Ddim);
            const int eo = w * 512 + l * 8;   // elements
            gload_lds16(ksrc + eo,        &Kt[0][0] + w * 512);
            gload_lds16(ksrc + eo + 2048, &Kt[0][0] + w * 512 + 2048);
            gload_lds16(vsrc + eo,        &Vt[0][0] + w * 512);
            gload_lds16(vsrc + eo + 2048, &Vt[0][0] + w * 512 + 2048);
        }
        __syncthreads();

        // S^T = mfma(K, Q), acc pre-biased with -m_run (lane's col q is fixed)
        f32x4 sa[4];
#pragma unroll
        for (int nt = 0; nt < 4; ++nt)
#pragma unroll
            for (int r = 0; r < 4; ++r) sa[nt][r] = -m_run;
        __builtin_amdgcn_s_setprio(1);
#pragma unroll
        for (int kc = 0; kc < 2; ++kc)
#pragma unroll
            for (int nt = 0; nt < 4; ++nt) {
                const short8 kf = *(const short8*)&Kt[nt * 16 + q][(kc * 32 + g * 8) ^ swz];
                sa[nt] = __builtin_amdgcn_mfma_f32_16x16x32_bf16(kf, qf[kc], sa[nt], 0, 0, 0);
            }
        __builtin_amdgcn_s_setprio(0);

        // row max (already shifted by -m_run)
        f32x4 m4 = sa[0];
#pragma unroll
        for (int nt = 1; nt < 4; ++nt)
#pragma unroll
            for (int r = 0; r < 4; ++r) m4[r] = fmaxf(m4[r], sa[nt][r]);
        float mx = fmaxf(fmaxf(m4[0], m4[1]), fmaxf(m4[2], m4[3]));
        mx = fmaxf(mx, __shfl_xor(mx, 16));
        mx = fmaxf(mx, __shfl_xor(mx, 32));

        PU pa[2];
        float ts = 0.0f;
        if (__all(mx <= DEFER_THR)) {
            // deferred: p = exp2(sa) directly — zero subtracts
#pragma unroll
            for (int nt = 0; nt < 4; ++nt) {
                float e0 = exp2f(sa[nt][0]), e1 = exp2f(sa[nt][1]);
                float e2 = exp2f(sa[nt][2]), e3 = exp2f(sa[nt][3]);
                ts += (e0 + e1) + (e2 + e3);
                pa[nt >> 1].u[(nt & 1) * 2 + 0] = cvt_pk_bf16(e0, e1);
                pa[nt >> 1].u[(nt & 1) * 2 + 1] = cvt_pk_bf16(e2, e3);
            }
            l_part += ts;
        } else {
            float fr = exp2f(-mx);
            m_run += mx;
#pragma unroll
            for (int nt = 0; nt < 4; ++nt) {
                float e0 = exp2f(sa[nt][0] - mx), e1 = exp2f(sa[nt][1] - mx);
                float e2 = exp2f(sa[nt][2] - mx), e3 = exp2f(sa[nt][3] - mx);
                ts += (e0 + e1) + (e2 + e3);
                pa[nt >> 1].u[(nt & 1) * 2 + 0] = cvt_pk_bf16(e0, e1);
                pa[nt >> 1].u[(nt & 1) * 2 + 1] = cvt_pk_bf16(e2, e3);
            }
            l_part = l_part * fr + ts;
            float frb[4];
#pragma unroll
            for (int r = 0; r < 4; ++r) frb[r] = __shfl(fr, 4 * g + r);
#pragma unroll
            for (int dt = 0; dt < 4; ++dt)
#pragma unroll
                for (int r = 0; r < 4; ++r) o[dt][r] *= frb[r];
        }

        // O += P V : pa is already the A-fragment (V was pre-permuted)
        __builtin_amdgcn_s_setprio(1);
#pragma unroll
        for (int kc = 0; kc < 2; ++kc)
#pragma unroll
            for (int dt = 0; dt < 4; ++dt) {
                const short8 vf = *(const short8*)&Vt[dt * 16 + q][(kc * 32 + g * 8) ^ swz];
                o[dt] = __builtin_amdgcn_mfma_f32_16x16x32_bf16(pa[kc].s8, vf, o[dt], 0, 0, 0);
            }
        __builtin_amdgcn_s_setprio(0);
    }

    // epilogue: reduce l partials across the 4 replicas, then scale+store
    l_part += __shfl_xor(l_part, 16);
    l_part += __shfl_xor(l_part, 32);
    float inv = 1.0f / l_part;
    float invb[4];
#pragma unroll
    for (int r = 0; r < 4; ++r) invb[r] = __shfl(inv, 4 * g + r);
#pragma unroll
    for (int r = 0; r < 4; ++r) {
        float* orow = Og + base + (size_t)(q0 + w * 16 + 4 * g + r) * Ddim;
#pragma unroll
        for (int dt = 0; dt < 4; ++dt) orow[dt * 16 + q] = o[dt][r] * invb[r];
    }
}

// ================= fallback (round-3 kernel, proven) =================
typedef __attribute__((ext_vector_type(2))) unsigned int uint2v;

__global__ __launch_bounds__(256, 4)
void attn_fwd_slow(const float* __restrict__ Qg, const float* __restrict__ Kg,
                   const float* __restrict__ Vg, float* __restrict__ Og)
{
    __shared__ unsigned short Kt[KVBLK][Ddim];
    __shared__ unsigned short Vt[Ddim][KVBLK];
    __shared__ unsigned short Pt[NW][16][KVBLK];

    const int tid = threadIdx.x;
    const int w   = tid >> 6;
    const int l   = tid & 63;
    const int g   = l >> 4;
    const int q   = l & 15;
    const int swz = (q & 7) << 3;

    const size_t base = (size_t)blockIdx.y * Sdim * Ddim;
    const int q0 = blockIdx.x * QBLK;

    short8 qf[2];
    {
        const float* qrow = Qg + base + (size_t)(q0 + w * 16 + q) * Ddim;
#pragma unroll
        for (int kc = 0; kc < 2; ++kc) {
            float fv[8];
            *(float4*)(fv)     = *(const float4*)(qrow + kc * 32 + g * 8);
            *(float4*)(fv + 4) = *(const float4*)(qrow + kc * 32 + g * 8 + 4);
            short8 r;
#pragma unroll
            for (int j = 0; j < 8; ++j) r[j] = (short)f2bf(fv[j] * QSCALE);
            qf[kc] = r;
        }
    }

    f32x4 o[4];
#pragma unroll
    for (int dt = 0; dt < 4; ++dt)
#pragma unroll
        for (int r = 0; r < 4; ++r) o[dt][r] = 0.0f;
    float m_run = -INFINITY, l_run = 0.0f;

    for (int t = 0; t < NT; ++t) {
        __syncthreads();
        {
            const float* Ksrc = Kg + base + (size_t)t * KVBLK * Ddim;
            const float* Vsrc = Vg + base + (size_t)t * KVBLK * Ddim;
#pragma unroll
            for (int it = 0; it < 4; ++it) {
                int idx = it * 1024 + tid * 4;
                int r = idx >> 6, c = idx & 63;
                float4 kf4 = *(const float4*)(Ksrc + idx);
                ushort4v hk;
                hk.x = f2bf(kf4.x); hk.y = f2bf(kf4.y);
                hk.z = f2bf(kf4.z); hk.w = f2bf(kf4.w);
                *(ushort4v*)&Kt[r][c ^ ((r & 7) << 3)] = hk;
            }
            {
                const int d = l;
                const int vswz = (d & 7) << 3;
#pragma unroll
                for (int i = 0; i < 4; ++i) {
                    int kv0 = w * 16 + i * 4;
                    float a0 = Vsrc[(size_t)(kv0 + 0) * Ddim + d];
                    float a1 = Vsrc[(size_t)(kv0 + 1) * Ddim + d];
                    float a2 = Vsrc[(size_t)(kv0 + 2) * Ddim + d];
                    float a3 = Vsrc[(size_t)(kv0 + 3) * Ddim + d];
                    ushort4v hv;
                    hv.x = f2bf(a0); hv.y = f2bf(a1);
                    hv.z = f2bf(a2); hv.w = f2bf(a3);
                    *(ushort4v*)&Vt[d][kv0 ^ vswz] = hv;
                }
            }
        }
        __syncthreads();

        f32x4 sa[4];
#pragma unroll
        for (int nt = 0; nt < 4; ++nt)
#pragma unroll
            for (int r = 0; r < 4; ++r) sa[nt][r] = 0.0f;
#pragma unroll
        for (int kc = 0; kc < 2; ++kc)
#pragma unroll
            for (int nt = 0; nt < 4; ++nt) {
                const short8 kf = *(const short8*)&Kt[nt * 16 + q][(kc * 32 + g * 8) ^ swz];
                sa[nt] = __builtin_amdgcn_mfma_f32_16x16x32_bf16(kf, qf[kc], sa[nt], 0, 0, 0);
            }

        float mx = sa[0][0];
#pragma unroll
        for (int nt = 0; nt < 4; ++nt)
#pragma unroll
            for (int r = 0; r < 4; ++r) mx = fmaxf(mx, sa[nt][r]);
        mx = fmaxf(mx, __shfl_xor(mx, 16));
        mx = fmaxf(mx, __shfl_xor(mx, 32));
        float mnew = fmaxf(m_run, mx);
        float fr = exp2f(m_run - mnew);
        m_run = mnew;

        float p[4][4];
        float s = 0.0f;
#pragma unroll
        for (int nt = 0; nt < 4; ++nt)
#pragma unroll
            for (int r = 0; r < 4; ++r) {
                float e = exp2f(sa[nt][r] - mnew);
                p[nt][r] = e; s += e;
            }
        s += __shfl_xor(s, 16);
        s += __shfl_xor(s, 32);
        l_run = l_run * fr + s;

#pragma unroll
        for (int nt = 0; nt < 4; ++nt) {
            uint2v pp;
            pp.x = cvt_pk_bf16(p[nt][0], p[nt][1]);
            pp.y = cvt_pk_bf16(p[nt][2], p[nt][3]);
            *(uint2v*)&Pt[w][q][(nt * 16 + 4 * g) ^ swz] = pp;
        }

        float frb[4];
#pragma unroll
        for (int r = 0; r < 4; ++r) frb[r] = __shfl(fr, 4 * g + r);
#pragma unroll
        for (int dt = 0; dt < 4; ++dt)
#pragma unroll
            for (int r = 0; r < 4; ++r) o[dt][r] *= frb[r];

#pragma unroll
        for (int kc = 0; kc < 2; ++kc) {
            const short8 pf = *(const short8*)&Pt[w][q][(kc * 32 + g * 8) ^ swz];
#pragma unroll
            for (int dt = 0; dt < 4; ++dt) {
                const short8 vf = *(const short8*)&Vt[dt * 16 + q][(kc * 32 + g * 8) ^ swz];
                o[dt] = __builtin_amdgcn_mfma_f32_16x16x32_bf16(pf, vf, o[dt], 0, 0, 0);
            }
        }
    }

    float inv = 1.0f / l_run;
    float invb[4];
#pragma unroll
    for (int r = 0; r < 4; ++r) invb[r] = __shfl(inv, 4 * g + r);
#pragma unroll
    for (int r = 0; r < 4; ++r) {
        float* orow = Og + base + (size_t)(q0 + w * 16 + 4 * g + r) * Ddim;
#pragma unroll
        for (int dt = 0; dt < 4; ++dt) orow[dt * 16 + q] = o[dt][r] * invb[r];
    }
}

extern "C" void kernel_launch(void* const* d_in, const int* in_sizes, int n_in,
                              void* d_out, int out_size, void* d_ws, size_t ws_size,
                              hipStream_t stream) {
    const float* Q = (const float*)d_in[0];
    const float* K = (const float*)d_in[1];
    const float* V = (const float*)d_in[2];
    float* O = (float*)d_out;
    const size_t elems = (size_t)NBH * Sdim * Ddim;          // 8.39M
    const size_t need  = elems * 2 * 2;                      // Kbf + Vtb, bf16
    dim3 grid(Sdim / QBLK, NBH);
    if (ws_size >= need) {
        unsigned short* Kbf = (unsigned short*)d_ws;
        unsigned short* Vtb = Kbf + elems;
        prep_k<<<dim3((unsigned)(elems / 4 / 256)), dim3(256), 0, stream>>>(K, Kbf);
        prep_v<<<dim3(NBH * NT), dim3(256), 0, stream>>>(V, Vtb);
        attn_fwd_fast<<<grid, dim3(256), 0, stream>>>(Q, Kbf, Vtb, O);
    } else {
        attn_fwd_slow<<<grid, dim3(256), 0, stream>>>(Q, K, V, O);
    }
}

// Round 7
// 249.477 us; speedup vs baseline: 2.0368x; 2.0368x over previous
//
#include <hip/hip_runtime.h>
#include <hip/hip_bf16.h>

// Attention fwd: B=4 H=16 S=2048 D=64, fp32 in/out, softmax(QK^T/8)V
// Round 7: round-6 math (V pre-permuted => cvt_pk IS the PV A-frag, acc-bias,
// per-lane l partials) + fixes: no forced occupancy (spill!), QBLK=128 with
// 8 waves, double-buffered K/V LDS, counted vmcnt + raw barriers (T3/T4).

constexpr int Sdim = 2048;
constexpr int Ddim = 64;
constexpr int QBLK = 128;           // main kernel: 8 waves x 16 q-rows
constexpr int KVBLK = 64;
constexpr int NBH = 64;             // B*H
constexpr int NT = Sdim / KVBLK;    // 32
constexpr int TILE_E = KVBLK * Ddim; // 4096 elems per K/V tile
constexpr float QSCALE = 0.125f * 1.44269504f; // 1/sqrt(64) * log2(e)
constexpr float DEFER_THR = 11.0f;  // log2 units: p <= 2^11

typedef __attribute__((ext_vector_type(8))) short short8;
typedef __attribute__((ext_vector_type(4))) float f32x4;
typedef __attribute__((ext_vector_type(4))) unsigned short ushort4v;
typedef __attribute__((ext_vector_type(2))) unsigned int uint2v;

typedef __attribute__((address_space(1))) const unsigned int GU32;
typedef __attribute__((address_space(3))) unsigned int LU32;

__device__ __forceinline__ unsigned short f2bf(float f) {
    union { float f; unsigned int u; } v; v.f = f;
    unsigned int r = v.u + 0x7FFFu + ((v.u >> 16) & 1u);   // RNE
    return (unsigned short)(r >> 16);
}

__device__ __forceinline__ unsigned int cvt_pk_bf16(float lo, float hi) {
    unsigned int r;
    asm("v_cvt_pk_bf16_f32 %0, %1, %2" : "=v"(r) : "v"(lo), "v"(hi));
    return r;
}

__device__ __forceinline__ void gload_lds16(const unsigned short* g, unsigned short* l) {
    __builtin_amdgcn_global_load_lds((GU32*)g, (LU32*)l, 16, 0, 0);
}

// ---- pre-pass: K -> bf16, swizzled within each row: elem (s, c) at c ^ ((s&7)<<3)
__global__ __launch_bounds__(256)
void prep_k(const float* __restrict__ Kg, unsigned short* __restrict__ Kbf) {
    size_t idx = ((size_t)blockIdx.x * 256 + threadIdx.x) * 4;
    int c0 = (int)(idx & 63);
    size_t row = idx >> 6;
    int swz = ((int)row & 7) << 3;
    float4 f = *(const float4*)(Kg + idx);
    ushort4v h;
    h.x = f2bf(f.x); h.y = f2bf(f.y); h.z = f2bf(f.z); h.w = f2bf(f.w);
    *(ushort4v*)(Kbf + (row << 6) + (c0 ^ swz)) = h;
}

// ---- pre-pass: V -> bf16, transposed + kv-PERMUTED per 64-tile:
// Vtb[d][ s ^ ((d&7)<<3) ] = V[kv][d]  with  s = 32kc+8g+4h+r  for
// kv = 32kc+16h+4g+r.  Coalesced via LDS-staged transpose. (verified r6)
__global__ __launch_bounds__(256)
void prep_v(const float* __restrict__ Vg, unsigned short* __restrict__ Vtb) {
    __shared__ unsigned short Vl[KVBLK][Ddim + 4];
    int bh = blockIdx.x >> 5, t = blockIdx.x & 31;
    const float* src = Vg + ((size_t)bh * Sdim + t * KVBLK) * Ddim;
    unsigned short* dst = Vtb + ((size_t)bh * NT + t) * TILE_E;

    {
        int kv = threadIdx.x >> 2;
        int dq = (threadIdx.x & 3) * 16;
#pragma unroll
        for (int i = 0; i < 4; ++i) {
            float4 f = *(const float4*)(src + (size_t)kv * Ddim + dq + 4 * i);
            ushort4v h;
            h.x = f2bf(f.x); h.y = f2bf(f.y); h.z = f2bf(f.z); h.w = f2bf(f.w);
            *(ushort4v*)&Vl[kv][dq + 4 * i] = h;
        }
    }
    __syncthreads();
    {
        int d  = threadIdx.x >> 2;
        int sc = (threadIdx.x & 3) * 16;
        int swzd = (d & 7) << 3;
#pragma unroll
        for (int u = 0; u < 4; ++u) {
            int s0 = sc + 4 * u;
            int kc = s0 >> 5, g = (s0 >> 3) & 3, h = (s0 >> 2) & 1;
            int kvb = 32 * kc + 16 * h + 4 * g;
            ushort4v o;
            o.x = Vl[kvb + 0][d]; o.y = Vl[kvb + 1][d];
            o.z = Vl[kvb + 2][d]; o.w = Vl[kvb + 3][d];
            *(ushort4v*)(dst + (size_t)d * KVBLK + (s0 ^ swzd)) = o;
        }
    }
}

// ================= fast main kernel =================
__global__ __launch_bounds__(512, 4)
void attn_fwd_fast(const float* __restrict__ Qg, const unsigned short* __restrict__ Kbf,
                   const unsigned short* __restrict__ Vtb, float* __restrict__ Og)
{
    __shared__ unsigned short Kt[2][KVBLK][Ddim];   // [buf][kv][d], row-swizzled
    __shared__ unsigned short Vt[2][Ddim][KVBLK];   // [buf][d][perm(kv)], row-swizzled

    const int tid = threadIdx.x;
    const int w   = tid >> 6;       // 0..7
    const int l   = tid & 63;
    const int g   = l >> 4;
    const int q   = l & 15;
    const int swz = (q & 7) << 3;

    const int bh = blockIdx.y;
    const size_t base = (size_t)bh * Sdim * Ddim;
    const int q0 = blockIdx.x * QBLK;

    const unsigned short* kbase = Kbf + base;
    const unsigned short* vbase = Vtb + base;
    const int eo = tid * 8;                 // elements; 512 thr x 16B = 8KB tile

    // Q fragments (B-operand of swapped QK^T), scale*log2e folded in
    short8 qf[2];
    {
        const float* qrow = Qg + base + (size_t)(q0 + w * 16 + q) * Ddim;
#pragma unroll
        for (int kc = 0; kc < 2; ++kc) {
            float fv[8];
            *(float4*)(fv)     = *(const float4*)(qrow + kc * 32 + g * 8);
            *(float4*)(fv + 4) = *(const float4*)(qrow + kc * 32 + g * 8 + 4);
            short8 r;
#pragma unroll
            for (int j = 0; j < 8; ++j) r[j] = (short)f2bf(fv[j] * QSCALE);
            qf[kc] = r;
        }
    }

    f32x4 o[4];
#pragma unroll
    for (int dt = 0; dt < 4; ++dt)
#pragma unroll
        for (int r = 0; r < 4; ++r) o[dt][r] = 0.0f;
    float m_run = 0.0f;      // log2-domain; defer bound keeps p<=2^11
    float l_part = 0.0f;     // per-lane partial; reduced in epilogue

    union PU { unsigned int u[4]; short8 s8; };

    // prologue: stage tile 0 into buf 0 (2 loads/thread)
    gload_lds16(kbase + eo, &Kt[0][0][0] + w * 512);
    gload_lds16(vbase + eo, &Vt[0][0][0] + w * 512);

    for (int t = 0; t < NT; ++t) {
        const int cur = t & 1;
        if (t + 1 < NT) {
            // stage next tile into the other buffer, then wait ONLY for tile t
            const unsigned short* kn = kbase + (size_t)(t + 1) * TILE_E;
            const unsigned short* vn = vbase + (size_t)(t + 1) * TILE_E;
            gload_lds16(kn + eo, &Kt[cur ^ 1][0][0] + w * 512);
            gload_lds16(vn + eo, &Vt[cur ^ 1][0][0] + w * 512);
            asm volatile("s_waitcnt vmcnt(2)" ::: "memory");
        } else {
            asm volatile("s_waitcnt vmcnt(0)" ::: "memory");
        }
        __builtin_amdgcn_s_barrier();           // all waves staged tile t
        __builtin_amdgcn_sched_barrier(0);

        // S^T = mfma(K, Q), acc pre-biased with -m_run
        f32x4 sa[4];
#pragma unroll
        for (int nt = 0; nt < 4; ++nt)
#pragma unroll
            for (int r = 0; r < 4; ++r) sa[nt][r] = -m_run;
        __builtin_amdgcn_s_setprio(1);
#pragma unroll
        for (int kc = 0; kc < 2; ++kc)
#pragma unroll
            for (int nt = 0; nt < 4; ++nt) {
                const short8 kf = *(const short8*)&Kt[cur][nt * 16 + q][(kc * 32 + g * 8) ^ swz];
                sa[nt] = __builtin_amdgcn_mfma_f32_16x16x32_bf16(kf, qf[kc], sa[nt], 0, 0, 0);
            }
        __builtin_amdgcn_s_setprio(0);

        // row max (already shifted by -m_run)
        f32x4 m4 = sa[0];
#pragma unroll
        for (int nt = 1; nt < 4; ++nt)
#pragma unroll
            for (int r = 0; r < 4; ++r) m4[r] = fmaxf(m4[r], sa[nt][r]);
        float mx = fmaxf(fmaxf(m4[0], m4[1]), fmaxf(m4[2], m4[3]));
        mx = fmaxf(mx, __shfl_xor(mx, 16));
        mx = fmaxf(mx, __shfl_xor(mx, 32));

        PU pa[2];
        float ts = 0.0f;
        if (__all(mx <= DEFER_THR)) {
#pragma unroll
            for (int nt = 0; nt < 4; ++nt) {
                float e0 = exp2f(sa[nt][0]), e1 = exp2f(sa[nt][1]);
                float e2 = exp2f(sa[nt][2]), e3 = exp2f(sa[nt][3]);
                ts += (e0 + e1) + (e2 + e3);
                pa[nt >> 1].u[(nt & 1) * 2 + 0] = cvt_pk_bf16(e0, e1);
                pa[nt >> 1].u[(nt & 1) * 2 + 1] = cvt_pk_bf16(e2, e3);
            }
            l_part += ts;
        } else {
            float fr = exp2f(-mx);
            m_run += mx;
#pragma unroll
            for (int nt = 0; nt < 4; ++nt) {
                float e0 = exp2f(sa[nt][0] - mx), e1 = exp2f(sa[nt][1] - mx);
                float e2 = exp2f(sa[nt][2] - mx), e3 = exp2f(sa[nt][3] - mx);
                ts += (e0 + e1) + (e2 + e3);
                pa[nt >> 1].u[(nt & 1) * 2 + 0] = cvt_pk_bf16(e0, e1);
                pa[nt >> 1].u[(nt & 1) * 2 + 1] = cvt_pk_bf16(e2, e3);
            }
            l_part = l_part * fr + ts;
            float frb[4];
#pragma unroll
            for (int r = 0; r < 4; ++r) frb[r] = __shfl(fr, 4 * g + r);
#pragma unroll
            for (int dt = 0; dt < 4; ++dt)
#pragma unroll
                for (int r = 0; r < 4; ++r) o[dt][r] *= frb[r];
        }

        // O += P V : pa is the A-fragment directly (V pre-permuted)
        __builtin_amdgcn_s_setprio(1);
#pragma unroll
        for (int kc = 0; kc < 2; ++kc)
#pragma unroll
            for (int dt = 0; dt < 4; ++dt) {
                const short8 vf = *(const short8*)&Vt[cur][dt * 16 + q][(kc * 32 + g * 8) ^ swz];
                o[dt] = __builtin_amdgcn_mfma_f32_16x16x32_bf16(pa[kc].s8, vf, o[dt], 0, 0, 0);
            }
        __builtin_amdgcn_s_setprio(0);

        if (t + 1 < NT) {
            __builtin_amdgcn_sched_barrier(0);
            __builtin_amdgcn_s_barrier();       // buf[cur] fully consumed
        }
    }

    // epilogue: reduce l partials, scale, store
    l_part += __shfl_xor(l_part, 16);
    l_part += __shfl_xor(l_part, 32);
    float inv = 1.0f / l_part;
    float invb[4];
#pragma unroll
    for (int r = 0; r < 4; ++r) invb[r] = __shfl(inv, 4 * g + r);
#pragma unroll
    for (int r = 0; r < 4; ++r) {
        float* orow = Og + base + (size_t)(q0 + w * 16 + 4 * g + r) * Ddim;
#pragma unroll
        for (int dt = 0; dt < 4; ++dt) orow[dt * 16 + q] = o[dt][r] * invb[r];
    }
}

// ================= fallback (round-3 kernel, proven) =================
__global__ __launch_bounds__(256, 4)
void attn_fwd_slow(const float* __restrict__ Qg, const float* __restrict__ Kg,
                   const float* __restrict__ Vg, float* __restrict__ Og)
{
    __shared__ unsigned short Kt[KVBLK][Ddim];
    __shared__ unsigned short Vt[Ddim][KVBLK];
    __shared__ unsigned short Pt[4][16][KVBLK];

    const int tid = threadIdx.x;
    const int w   = tid >> 6;
    const int l   = tid & 63;
    const int g   = l >> 4;
    const int q   = l & 15;
    const int swz = (q & 7) << 3;

    const size_t base = (size_t)blockIdx.y * Sdim * Ddim;
    const int q0 = blockIdx.x * 64;

    short8 qf[2];
    {
        const float* qrow = Qg + base + (size_t)(q0 + w * 16 + q) * Ddim;
#pragma unroll
        for (int kc = 0; kc < 2; ++kc) {
            float fv[8];
            *(float4*)(fv)     = *(const float4*)(qrow + kc * 32 + g * 8);
            *(float4*)(fv + 4) = *(const float4*)(qrow + kc * 32 + g * 8 + 4);
            short8 r;
#pragma unroll
            for (int j = 0; j < 8; ++j) r[j] = (short)f2bf(fv[j] * QSCALE);
            qf[kc] = r;
        }
    }

    f32x4 o[4];
#pragma unroll
    for (int dt = 0; dt < 4; ++dt)
#pragma unroll
        for (int r = 0; r < 4; ++r) o[dt][r] = 0.0f;
    float m_run = -INFINITY, l_run = 0.0f;

    for (int t = 0; t < NT; ++t) {
        __syncthreads();
        {
            const float* Ksrc = Kg + base + (size_t)t * KVBLK * Ddim;
            const float* Vsrc = Vg + base + (size_t)t * KVBLK * Ddim;
#pragma unroll
            for (int it = 0; it < 4; ++it) {
                int idx = it * 1024 + tid * 4;
                int r = idx >> 6, c = idx & 63;
                float4 kf4 = *(const float4*)(Ksrc + idx);
                ushort4v hk;
                hk.x = f2bf(kf4.x); hk.y = f2bf(kf4.y);
                hk.z = f2bf(kf4.z); hk.w = f2bf(kf4.w);
                *(ushort4v*)&Kt[r][c ^ ((r & 7) << 3)] = hk;
            }
            {
                const int d = l;
                const int vswz = (d & 7) << 3;
#pragma unroll
                for (int i = 0; i < 4; ++i) {
                    int kv0 = w * 16 + i * 4;
                    float a0 = Vsrc[(size_t)(kv0 + 0) * Ddim + d];
                    float a1 = Vsrc[(size_t)(kv0 + 1) * Ddim + d];
                    float a2 = Vsrc[(size_t)(kv0 + 2) * Ddim + d];
                    float a3 = Vsrc[(size_t)(kv0 + 3) * Ddim + d];
                    ushort4v hv;
                    hv.x = f2bf(a0); hv.y = f2bf(a1);
                    hv.z = f2bf(a2); hv.w = f2bf(a3);
                    *(ushort4v*)&Vt[d][kv0 ^ vswz] = hv;
                }
            }
        }
        __syncthreads();

        f32x4 sa[4];
#pragma unroll
        for (int nt = 0; nt < 4; ++nt)
#pragma unroll
            for (int r = 0; r < 4; ++r) sa[nt][r] = 0.0f;
#pragma unroll
        for (int kc = 0; kc < 2; ++kc)
#pragma unroll
            for (int nt = 0; nt < 4; ++nt) {
                const short8 kf = *(const short8*)&Kt[nt * 16 + q][(kc * 32 + g * 8) ^ swz];
                sa[nt] = __builtin_amdgcn_mfma_f32_16x16x32_bf16(kf, qf[kc], sa[nt], 0, 0, 0);
            }

        float mx = sa[0][0];
#pragma unroll
        for (int nt = 0; nt < 4; ++nt)
#pragma unroll
            for (int r = 0; r < 4; ++r) mx = fmaxf(mx, sa[nt][r]);
        mx = fmaxf(mx, __shfl_xor(mx, 16));
        mx = fmaxf(mx, __shfl_xor(mx, 32));
        float mnew = fmaxf(m_run, mx);
        float fr = exp2f(m_run - mnew);
        m_run = mnew;

        float p[4][4];
        float s = 0.0f;
#pragma unroll
        for (int nt = 0; nt < 4; ++nt)
#pragma unroll
            for (int r = 0; r < 4; ++r) {
                float e = exp2f(sa[nt][r] - mnew);
                p[nt][r] = e; s += e;
            }
        s += __shfl_xor(s, 16);
        s += __shfl_xor(s, 32);
        l_run = l_run * fr + s;

#pragma unroll
        for (int nt = 0; nt < 4; ++nt) {
            uint2v pp;
            pp.x = cvt_pk_bf16(p[nt][0], p[nt][1]);
            pp.y = cvt_pk_bf16(p[nt][2], p[nt][3]);
            *(uint2v*)&Pt[w][q][(nt * 16 + 4 * g) ^ swz] = pp;
        }

        float frb[4];
#pragma unroll
        for (int r = 0; r < 4; ++r) frb[r] = __shfl(fr, 4 * g + r);
#pragma unroll
        for (int dt = 0; dt < 4; ++dt)
#pragma unroll
            for (int r = 0; r < 4; ++r) o[dt][r] *= frb[r];

#pragma unroll
        for (int kc = 0; kc < 2; ++kc) {
            const short8 pf = *(const short8*)&Pt[w][q][(kc * 32 + g * 8) ^ swz];
#pragma unroll
            for (int dt = 0; dt < 4; ++dt) {
                const short8 vf = *(const short8*)&Vt[dt * 16 + q][(kc * 32 + g * 8) ^ swz];
                o[dt] = __builtin_amdgcn_mfma_f32_16x16x32_bf16(pf, vf, o[dt], 0, 0, 0);
            }
        }
    }

    float inv = 1.0f / l_run;
    float invb[4];
#pragma unroll
    for (int r = 0; r < 4; ++r) invb[r] = __shfl(inv, 4 * g + r);
#pragma unroll
    for (int r = 0; r < 4; ++r) {
        float* orow = Og + base + (size_t)(q0 + w * 16 + 4 * g + r) * Ddim;
#pragma unroll
        for (int dt = 0; dt < 4; ++dt) orow[dt * 16 + q] = o[dt][r] * invb[r];
    }
}

extern "C" void kernel_launch(void* const* d_in, const int* in_sizes, int n_in,
                              void* d_out, int out_size, void* d_ws, size_t ws_size,
                              hipStream_t stream) {
    const float* Q = (const float*)d_in[0];
    const float* K = (const float*)d_in[1];
    const float* V = (const float*)d_in[2];
    float* O = (float*)d_out;
    const size_t elems = (size_t)NBH * Sdim * Ddim;          // 8.39M
    const size_t need  = elems * 2 * 2;                      // Kbf + Vtb, bf16
    if (ws_size >= need) {
        unsigned short* Kbf = (unsigned short*)d_ws;
        unsigned short* Vtb = Kbf + elems;
        prep_k<<<dim3((unsigned)(elems / 4 / 256)), dim3(256), 0, stream>>>(K, Kbf);
        prep_v<<<dim3(NBH * NT), dim3(256), 0, stream>>>(V, Vtb);
        attn_fwd_fast<<<dim3(Sdim / QBLK, NBH), dim3(512), 0, stream>>>(Q, Kbf, Vtb, O);
    } else {
        attn_fwd_slow<<<dim3(Sdim / 64, NBH), dim3(256), 0, stream>>>(Q, K, V, O);
    }
}

// Round 8
// 248.009 us; speedup vs baseline: 2.0488x; 1.0059x over previous
//
#include <hip/hip_runtime.h>
#include <hip/hip_bf16.h>

// Attention fwd: B=4 H=16 S=2048 D=64, fp32 in/out, softmax(QK^T/8)V
// Round 8: triple-buffered K/V LDS with ONE barrier per tile (issue-after-
// barrier + blanket vmcnt(4)), PV MFMAs moved inside the softmax branch and
// interleaved per kv-half with exp2/cvt (dual-pipe overlap), merged prep.

constexpr int Sdim = 2048;
constexpr int Ddim = 64;
constexpr int QBLK = 128;           // 8 waves x 16 q-rows
constexpr int KVBLK = 64;
constexpr int NBH = 64;             // B*H
constexpr int NT = Sdim / KVBLK;    // 32
constexpr int TILE_E = KVBLK * Ddim; // 4096 elems per K/V tile
constexpr float QSCALE = 0.125f * 1.44269504f; // 1/sqrt(64) * log2(e)
constexpr float DEFER_THR = 11.0f;  // log2 units: p <= 2^11

typedef __attribute__((ext_vector_type(8))) short short8;
typedef __attribute__((ext_vector_type(4))) float f32x4;
typedef __attribute__((ext_vector_type(4))) unsigned short ushort4v;
typedef __attribute__((ext_vector_type(2))) unsigned int uint2v;

typedef __attribute__((address_space(1))) const unsigned int GU32;
typedef __attribute__((address_space(3))) unsigned int LU32;

__device__ __forceinline__ unsigned short f2bf(float f) {
    union { float f; unsigned int u; } v; v.f = f;
    unsigned int r = v.u + 0x7FFFu + ((v.u >> 16) & 1u);   // RNE
    return (unsigned short)(r >> 16);
}

__device__ __forceinline__ unsigned int cvt_pk_bf16(float lo, float hi) {
    unsigned int r;
    asm("v_cvt_pk_bf16_f32 %0, %1, %2" : "=v"(r) : "v"(lo), "v"(hi));
    return r;
}

__device__ __forceinline__ void gload_lds16(const unsigned short* g, unsigned short* l) {
    __builtin_amdgcn_global_load_lds((GU32*)g, (LU32*)l, 16, 0, 0);
}

// ---- merged pre-pass ----
// blocks [0, KPB): K -> bf16, row-swizzled: elem (s,c) at c ^ ((s&7)<<3)
// blocks [KPB, KPB+VPB): V -> bf16 transposed + kv-permuted per 64-tile:
//   Vtb[d][ s ^ ((d&7)<<3) ] = V[kv][d],  s = 32kc+8g+4h+r for kv = 32kc+16h+4g+r
constexpr int KPB = (NBH * Sdim * Ddim) / 4 / 256;   // 8192
constexpr int VPB = NBH * NT;                        // 2048

__global__ __launch_bounds__(256)
void prep_kv(const float* __restrict__ Kg, const float* __restrict__ Vg,
             unsigned short* __restrict__ Kbf, unsigned short* __restrict__ Vtb) {
    __shared__ unsigned short Vl[KVBLK][Ddim + 4];
    if (blockIdx.x < KPB) {
        size_t idx = ((size_t)blockIdx.x * 256 + threadIdx.x) * 4;
        int c0 = (int)(idx & 63);
        size_t row = idx >> 6;
        int swz = ((int)row & 7) << 3;
        float4 f = *(const float4*)(Kg + idx);
        ushort4v h;
        h.x = f2bf(f.x); h.y = f2bf(f.y); h.z = f2bf(f.z); h.w = f2bf(f.w);
        *(ushort4v*)(Kbf + (row << 6) + (c0 ^ swz)) = h;
        return;
    }
    int bid = blockIdx.x - KPB;
    int bh = bid >> 5, t = bid & 31;
    const float* src = Vg + ((size_t)bh * Sdim + t * KVBLK) * Ddim;
    unsigned short* dst = Vtb + ((size_t)bh * NT + t) * TILE_E;
    {
        int kv = threadIdx.x >> 2;
        int dq = (threadIdx.x & 3) * 16;
#pragma unroll
        for (int i = 0; i < 4; ++i) {
            float4 f = *(const float4*)(src + (size_t)kv * Ddim + dq + 4 * i);
            ushort4v h;
            h.x = f2bf(f.x); h.y = f2bf(f.y); h.z = f2bf(f.z); h.w = f2bf(f.w);
            *(ushort4v*)&Vl[kv][dq + 4 * i] = h;
        }
    }
    __syncthreads();
    {
        int d  = threadIdx.x >> 2;
        int sc = (threadIdx.x & 3) * 16;
        int swzd = (d & 7) << 3;
#pragma unroll
        for (int u = 0; u < 4; ++u) {
            int s0 = sc + 4 * u;
            int kc = s0 >> 5, g = (s0 >> 3) & 3, h = (s0 >> 2) & 1;
            int kvb = 32 * kc + 16 * h + 4 * g;
            ushort4v o;
            o.x = Vl[kvb + 0][d]; o.y = Vl[kvb + 1][d];
            o.z = Vl[kvb + 2][d]; o.w = Vl[kvb + 3][d];
            *(ushort4v*)(dst + (size_t)d * KVBLK + (s0 ^ swzd)) = o;
        }
    }
}

// ================= fast main kernel =================
__global__ __launch_bounds__(512, 4)
void attn_fwd_fast(const float* __restrict__ Qg, const unsigned short* __restrict__ Kbf,
                   const unsigned short* __restrict__ Vtb, float* __restrict__ Og)
{
    __shared__ unsigned short Kt[3][KVBLK][Ddim];   // [buf][kv][d], row-swizzled
    __shared__ unsigned short Vt[3][KVBLK][Ddim];   // [buf][d][perm(kv)], row-swizzled

    const int tid = threadIdx.x;
    const int w   = tid >> 6;       // 0..7
    const int l   = tid & 63;
    const int g   = l >> 4;
    const int q   = l & 15;
    const int swz = (q & 7) << 3;

    const int bh = blockIdx.y;
    const size_t base = (size_t)bh * Sdim * Ddim;
    const int q0 = blockIdx.x * QBLK;

    const unsigned short* kbase = Kbf + base;
    const unsigned short* vbase = Vtb + base;
    const int eo = tid * 8;                  // 512 thr x 16B = one 8KB tile
    const int stoff = w * 512;               // wave-uniform LDS dest (elements)

    // Q fragments (B-operand of swapped QK^T), scale*log2e folded in
    short8 qf[2];
    {
        const float* qrow = Qg + base + (size_t)(q0 + w * 16 + q) * Ddim;
#pragma unroll
        for (int kc = 0; kc < 2; ++kc) {
            float fv[8];
            *(float4*)(fv)     = *(const float4*)(qrow + kc * 32 + g * 8);
            *(float4*)(fv + 4) = *(const float4*)(qrow + kc * 32 + g * 8 + 4);
            short8 r;
#pragma unroll
            for (int j = 0; j < 8; ++j) r[j] = (short)f2bf(fv[j] * QSCALE);
            qf[kc] = r;
        }
    }

    f32x4 o[4];
#pragma unroll
    for (int dt = 0; dt < 4; ++dt)
#pragma unroll
        for (int r = 0; r < 4; ++r) o[dt][r] = 0.0f;
    float m_run = 0.0f;      // log2-domain; defer bound keeps p<=2^11
    float l_part = 0.0f;     // per-lane partial; reduced in epilogue

    union PU { unsigned int u[2]; short8 s8; unsigned long long ll; };

    // rotating LDS buffer pointers: b0 = compute, b1 = next, b2 = stage target
    unsigned short* k0 = &Kt[0][0][0];
    unsigned short* k1 = &Kt[1][0][0];
    unsigned short* k2 = &Kt[2][0][0];
    unsigned short* v0 = &Vt[0][0][0];
    unsigned short* v1 = &Vt[1][0][0];
    unsigned short* v2 = &Vt[2][0][0];

    // prologue: stage tiles 0,1
    gload_lds16(kbase + eo,          k0 + stoff);
    gload_lds16(vbase + eo,          v0 + stoff);
    gload_lds16(kbase + TILE_E + eo, k1 + stoff);
    gload_lds16(vbase + TILE_E + eo, v1 + stoff);

    for (int t = 0; t < NT; ++t) {
        __builtin_amdgcn_s_barrier();   // tile t staged by all; buf b2's old readers done
        if (t + 2 < NT) {
            const size_t toff = (size_t)(t + 2) * TILE_E + eo;
            gload_lds16(kbase + toff, k2 + stoff);
            gload_lds16(vbase + toff, v2 + stoff);
        }
        // wait for tile t only (<=4 newer loads outstanding; in-order retire)
        asm volatile("s_waitcnt vmcnt(4)" ::: "memory");
        __builtin_amdgcn_sched_barrier(0);

        // S^T = mfma(K, Q), acc pre-biased with -m_run
        f32x4 sa[4];
#pragma unroll
        for (int nt = 0; nt < 4; ++nt)
#pragma unroll
            for (int r = 0; r < 4; ++r) sa[nt][r] = -m_run;
        __builtin_amdgcn_s_setprio(1);
#pragma unroll
        for (int kc = 0; kc < 2; ++kc)
#pragma unroll
            for (int nt = 0; nt < 4; ++nt) {
                const short8 kf = *(const short8*)(k0 + (nt * 16 + q) * Ddim + ((kc * 32 + g * 8) ^ swz));
                sa[nt] = __builtin_amdgcn_mfma_f32_16x16x32_bf16(kf, qf[kc], sa[nt], 0, 0, 0);
            }
        __builtin_amdgcn_s_setprio(0);

        // row max (already shifted by -m_run)
        f32x4 m4 = sa[0];
#pragma unroll
        for (int nt = 1; nt < 4; ++nt)
#pragma unroll
            for (int r = 0; r < 4; ++r) m4[r] = fmaxf(m4[r], sa[nt][r]);
        float mx = fmaxf(fmaxf(m4[0], m4[1]), fmaxf(m4[2], m4[3]));
        mx = fmaxf(mx, __shfl_xor(mx, 16));
        mx = fmaxf(mx, __shfl_xor(mx, 32));

        if (__all(mx <= DEFER_THR)) {
            // deferred: p = exp2(sa). Per kv-half: exp/cvt (VALU) then 4 MFMA
            // (matrix pipe) -> halves overlap across pipes.
            PU pa0, pa1;
            float ts = 0.0f;
            {
                float e0 = exp2f(sa[0][0]), e1 = exp2f(sa[0][1]);
                float e2 = exp2f(sa[0][2]), e3 = exp2f(sa[0][3]);
                float e4 = exp2f(sa[1][0]), e5 = exp2f(sa[1][1]);
                float e6 = exp2f(sa[1][2]), e7 = exp2f(sa[1][3]);
                ts += (e0 + e1) + (e2 + e3) + (e4 + e5) + (e6 + e7);
                pa0.u[0] = cvt_pk_bf16(e0, e1);
                pa0.u[1] = cvt_pk_bf16(e2, e3);
                pa0.ll = (unsigned long long)pa0.u[0] | ((unsigned long long)pa0.u[1] << 32);
                ((unsigned int*)&pa0)[2] = cvt_pk_bf16(e4, e5);
                ((unsigned int*)&pa0)[3] = cvt_pk_bf16(e6, e7);
            }
            __builtin_amdgcn_s_setprio(1);
#pragma unroll
            for (int dt = 0; dt < 4; ++dt) {
                const short8 vf = *(const short8*)(v0 + (dt * 16 + q) * Ddim + ((0 * 32 + g * 8) ^ swz));
                o[dt] = __builtin_amdgcn_mfma_f32_16x16x32_bf16(pa0.s8, vf, o[dt], 0, 0, 0);
            }
            __builtin_amdgcn_s_setprio(0);
            {
                float e0 = exp2f(sa[2][0]), e1 = exp2f(sa[2][1]);
                float e2 = exp2f(sa[2][2]), e3 = exp2f(sa[2][3]);
                float e4 = exp2f(sa[3][0]), e5 = exp2f(sa[3][1]);
                float e6 = exp2f(sa[3][2]), e7 = exp2f(sa[3][3]);
                ts += (e0 + e1) + (e2 + e3) + (e4 + e5) + (e6 + e7);
                ((unsigned int*)&pa1)[0] = cvt_pk_bf16(e0, e1);
                ((unsigned int*)&pa1)[1] = cvt_pk_bf16(e2, e3);
                ((unsigned int*)&pa1)[2] = cvt_pk_bf16(e4, e5);
                ((unsigned int*)&pa1)[3] = cvt_pk_bf16(e6, e7);
            }
            __builtin_amdgcn_s_setprio(1);
#pragma unroll
            for (int dt = 0; dt < 4; ++dt) {
                const short8 vf = *(const short8*)(v0 + (dt * 16 + q) * Ddim + ((1 * 32 + g * 8) ^ swz));
                o[dt] = __builtin_amdgcn_mfma_f32_16x16x32_bf16(pa1.s8, vf, o[dt], 0, 0, 0);
            }
            __builtin_amdgcn_s_setprio(0);
            l_part += ts;
        } else {
            float fr = exp2f(-mx);
            m_run += mx;
            PU pa0, pa1;
            float ts = 0.0f;
#pragma unroll
            for (int nt = 0; nt < 4; ++nt) {
                float e0 = exp2f(sa[nt][0] - mx), e1 = exp2f(sa[nt][1] - mx);
                float e2 = exp2f(sa[nt][2] - mx), e3 = exp2f(sa[nt][3] - mx);
                ts += (e0 + e1) + (e2 + e3);
                PU& pp = (nt < 2) ? pa0 : pa1;
                ((unsigned int*)&pp)[(nt & 1) * 2 + 0] = cvt_pk_bf16(e0, e1);
                ((unsigned int*)&pp)[(nt & 1) * 2 + 1] = cvt_pk_bf16(e2, e3);
            }
            l_part = l_part * fr + ts;
            float frb[4];
#pragma unroll
            for (int r = 0; r < 4; ++r) frb[r] = __shfl(fr, 4 * g + r);
#pragma unroll
            for (int dt = 0; dt < 4; ++dt)
#pragma unroll
                for (int r = 0; r < 4; ++r) o[dt][r] *= frb[r];
            __builtin_amdgcn_s_setprio(1);
#pragma unroll
            for (int kc = 0; kc < 2; ++kc)
#pragma unroll
                for (int dt = 0; dt < 4; ++dt) {
                    const short8 vf = *(const short8*)(v0 + (dt * 16 + q) * Ddim + ((kc * 32 + g * 8) ^ swz));
                    o[dt] = __builtin_amdgcn_mfma_f32_16x16x32_bf16((kc ? pa1 : pa0).s8, vf, o[dt], 0, 0, 0);
                }
            __builtin_amdgcn_s_setprio(0);
        }

        // rotate buffers
        unsigned short* tk = k0; k0 = k1; k1 = k2; k2 = tk;
        unsigned short* tv = v0; v0 = v1; v1 = v2; v2 = tv;
    }

    // epilogue: reduce l partials, scale, store
    l_part += __shfl_xor(l_part, 16);
    l_part += __shfl_xor(l_part, 32);
    float inv = 1.0f / l_part;
    float invb[4];
#pragma unroll
    for (int r = 0; r < 4; ++r) invb[r] = __shfl(inv, 4 * g + r);
#pragma unroll
    for (int r = 0; r < 4; ++r) {
        float* orow = Og + base + (size_t)(q0 + w * 16 + 4 * g + r) * Ddim;
#pragma unroll
        for (int dt = 0; dt < 4; ++dt) orow[dt * 16 + q] = o[dt][r] * invb[r];
    }
}

// ================= fallback (round-3 kernel, proven) =================
__global__ __launch_bounds__(256, 4)
void attn_fwd_slow(const float* __restrict__ Qg, const float* __restrict__ Kg,
                   const float* __restrict__ Vg, float* __restrict__ Og)
{
    __shared__ unsigned short Kt[KVBLK][Ddim];
    __shared__ unsigned short Vt[Ddim][KVBLK];
    __shared__ unsigned short Pt[4][16][KVBLK];

    const int tid = threadIdx.x;
    const int w   = tid >> 6;
    const int l   = tid & 63;
    const int g   = l >> 4;
    const int q   = l & 15;
    const int swz = (q & 7) << 3;

    const size_t base = (size_t)blockIdx.y * Sdim * Ddim;
    const int q0 = blockIdx.x * 64;

    short8 qf[2];
    {
        const float* qrow = Qg + base + (size_t)(q0 + w * 16 + q) * Ddim;
#pragma unroll
        for (int kc = 0; kc < 2; ++kc) {
            float fv[8];
            *(float4*)(fv)     = *(const float4*)(qrow + kc * 32 + g * 8);
            *(float4*)(fv + 4) = *(const float4*)(qrow + kc * 32 + g * 8 + 4);
            short8 r;
#pragma unroll
            for (int j = 0; j < 8; ++j) r[j] = (short)f2bf(fv[j] * QSCALE);
            qf[kc] = r;
        }
    }

    f32x4 o[4];
#pragma unroll
    for (int dt = 0; dt < 4; ++dt)
#pragma unroll
        for (int r = 0; r < 4; ++r) o[dt][r] = 0.0f;
    float m_run = -INFINITY, l_run = 0.0f;

    for (int t = 0; t < NT; ++t) {
        __syncthreads();
        {
            const float* Ksrc = Kg + base + (size_t)t * KVBLK * Ddim;
            const float* Vsrc = Vg + base + (size_t)t * KVBLK * Ddim;
#pragma unroll
            for (int it = 0; it < 4; ++it) {
                int idx = it * 1024 + tid * 4;
                int r = idx >> 6, c = idx & 63;
                float4 kf4 = *(const float4*)(Ksrc + idx);
                ushort4v hk;
                hk.x = f2bf(kf4.x); hk.y = f2bf(kf4.y);
                hk.z = f2bf(kf4.z); hk.w = f2bf(kf4.w);
                *(ushort4v*)&Kt[r][c ^ ((r & 7) << 3)] = hk;
            }
            {
                const int d = l;
                const int vswz = (d & 7) << 3;
#pragma unroll
                for (int i = 0; i < 4; ++i) {
                    int kv0 = w * 16 + i * 4;
                    float a0 = Vsrc[(size_t)(kv0 + 0) * Ddim + d];
                    float a1 = Vsrc[(size_t)(kv0 + 1) * Ddim + d];
                    float a2 = Vsrc[(size_t)(kv0 + 2) * Ddim + d];
                    float a3 = Vsrc[(size_t)(kv0 + 3) * Ddim + d];
                    ushort4v hv;
                    hv.x = f2bf(a0); hv.y = f2bf(a1);
                    hv.z = f2bf(a2); hv.w = f2bf(a3);
                    *(ushort4v*)&Vt[d][kv0 ^ vswz] = hv;
                }
            }
        }
        __syncthreads();

        f32x4 sa[4];
#pragma unroll
        for (int nt = 0; nt < 4; ++nt)
#pragma unroll
            for (int r = 0; r < 4; ++r) sa[nt][r] = 0.0f;
#pragma unroll
        for (int kc = 0; kc < 2; ++kc)
#pragma unroll
            for (int nt = 0; nt < 4; ++nt) {
                const short8 kf = *(const short8*)&Kt[nt * 16 + q][(kc * 32 + g * 8) ^ swz];
                sa[nt] = __builtin_amdgcn_mfma_f32_16x16x32_bf16(kf, qf[kc], sa[nt], 0, 0, 0);
            }

        float mx = sa[0][0];
#pragma unroll
        for (int nt = 0; nt < 4; ++nt)
#pragma unroll
            for (int r = 0; r < 4; ++r) mx = fmaxf(mx, sa[nt][r]);
        mx = fmaxf(mx, __shfl_xor(mx, 16));
        mx = fmaxf(mx, __shfl_xor(mx, 32));
        float mnew = fmaxf(m_run, mx);
        float fr = exp2f(m_run - mnew);
        m_run = mnew;

        float p[4][4];
        float s = 0.0f;
#pragma unroll
        for (int nt = 0; nt < 4; ++nt)
#pragma unroll
            for (int r = 0; r < 4; ++r) {
                float e = exp2f(sa[nt][r] - mnew);
                p[nt][r] = e; s += e;
            }
        s += __shfl_xor(s, 16);
        s += __shfl_xor(s, 32);
        l_run = l_run * fr + s;

#pragma unroll
        for (int nt = 0; nt < 4; ++nt) {
            uint2v pp;
            pp.x = cvt_pk_bf16(p[nt][0], p[nt][1]);
            pp.y = cvt_pk_bf16(p[nt][2], p[nt][3]);
            *(uint2v*)&Pt[w][q][(nt * 16 + 4 * g) ^ swz] = pp;
        }

        float frb[4];
#pragma unroll
        for (int r = 0; r < 4; ++r) frb[r] = __shfl(fr, 4 * g + r);
#pragma unroll
        for (int dt = 0; dt < 4; ++dt)
#pragma unroll
            for (int r = 0; r < 4; ++r) o[dt][r] *= frb[r];

#pragma unroll
        for (int kc = 0; kc < 2; ++kc) {
            const short8 pf = *(const short8*)&Pt[w][q][(kc * 32 + g * 8) ^ swz];
#pragma unroll
            for (int dt = 0; dt < 4; ++dt) {
                const short8 vf = *(const short8*)&Vt[dt * 16 + q][(kc * 32 + g * 8) ^ swz];
                o[dt] = __builtin_amdgcn_mfma_f32_16x16x32_bf16(pf, vf, o[dt], 0, 0, 0);
            }
        }
    }

    float inv = 1.0f / l_run;
    float invb[4];
#pragma unroll
    for (int r = 0; r < 4; ++r) invb[r] = __shfl(inv, 4 * g + r);
#pragma unroll
    for (int r = 0; r < 4; ++r) {
        float* orow = Og + base + (size_t)(q0 + w * 16 + 4 * g + r) * Ddim;
#pragma unroll
        for (int dt = 0; dt < 4; ++dt) orow[dt * 16 + q] = o[dt][r] * invb[r];
    }
}

extern "C" void kernel_launch(void* const* d_in, const int* in_sizes, int n_in,
                              void* d_out, int out_size, void* d_ws, size_t ws_size,
                              hipStream_t stream) {
    const float* Q = (const float*)d_in[0];
    const float* K = (const float*)d_in[1];
    const float* V = (const float*)d_in[2];
    float* O = (float*)d_out;
    const size_t elems = (size_t)NBH * Sdim * Ddim;          // 8.39M
    const size_t need  = elems * 2 * 2;                      // Kbf + Vtb, bf16
    if (ws_size >= need) {
        unsigned short* Kbf = (unsigned short*)d_ws;
        unsigned short* Vtb = Kbf + elems;
        prep_kv<<<dim3(KPB + VPB), dim3(256), 0, stream>>>(K, V, Kbf, Vtb);
        attn_fwd_fast<<<dim3(Sdim / QBLK, NBH), dim3(512), 0, stream>>>(Q, Kbf, Vtb, O);
    } else {
        attn_fwd_slow<<<dim3(Sdim / 64, NBH), dim3(256), 0, stream>>>(Q, K, V, O);
    }
}